// Round 1
// baseline (2872.911 us; speedup 1.0000x reference)
//
#include <hip/hip_runtime.h>
#include <hip/hip_bf16.h>

#define NB 16
#define NN 4096
#define NS 1024
#define NK 32
#define CF 64
#define CIN 67
#define MTOT 524288          // NB*NS*NK
#define NEWP_OFF 49152       // NB*NS*3

__device__ inline unsigned long long shflxor64(unsigned long long v, int m) {
    int lo = __shfl_xor((int)(unsigned)(v & 0xffffffffULL), m);
    int hi = __shfl_xor((int)(unsigned)(v >> 32), m);
    return ((unsigned long long)(unsigned)hi << 32) | (unsigned)lo;
}

__device__ inline void stY(float* p, float v) { *p = v; }
__device__ inline void stY(__hip_bfloat16* p, float v) { *p = __float2bfloat16(v); }
__device__ inline float ldY(const float* p) { return *p; }
__device__ inline float ldY(const __hip_bfloat16* p) { return __bfloat162float(*p); }

// ---------------- FPS: 16 blocks (one per batch), 1024 threads, 4 pts/thread ----
__global__ __launch_bounds__(1024) void fps_kernel(const float* __restrict__ xyz,
                                                   int* __restrict__ fps_idx) {
    __shared__ float lx[NN], ly[NN], lz[NN];
    __shared__ unsigned long long part[2][16];
    const int b = blockIdx.x, t = threadIdx.x;
    const float4* src = (const float4*)(xyz + (size_t)b * NN * 3);
    float4 A = src[t * 3 + 0], B4 = src[t * 3 + 1], C4 = src[t * 3 + 2];
    float px[4] = {A.x, A.w, B4.z, C4.y};
    float py[4] = {A.y, B4.x, B4.w, C4.z};
    float pz[4] = {A.z, B4.y, C4.x, C4.w};
    float dist[4] = {1e10f, 1e10f, 1e10f, 1e10f};
#pragma unroll
    for (int i = 0; i < 4; ++i) { lx[4*t+i] = px[i]; ly[4*t+i] = py[i]; lz[4*t+i] = pz[i]; }
    __syncthreads();
    int cur = 0;
    float cx = lx[0], cy = ly[0], cz = lz[0];
    const int lane = t & 63;
    for (int s = 0; s < NS; ++s) {
        if (t == 0) fps_idx[(b << 10) + s] = cur;
        unsigned long long best = 0;
#pragma unroll
        for (int i = 0; i < 4; ++i) {
            float dx = __fsub_rn(px[i], cx), dy = __fsub_rn(py[i], cy), dz = __fsub_rn(pz[i], cz);
            float d = __fadd_rn(__fadd_rn(__fmul_rn(dx, dx), __fmul_rn(dy, dy)), __fmul_rn(dz, dz));
            dist[i] = fminf(dist[i], d);
            unsigned long long key =
                ((unsigned long long)__float_as_uint(dist[i]) << 32) | (unsigned)(4095 - (4 * t + i));
            best = key > best ? key : best;
        }
#pragma unroll
        for (int m = 32; m; m >>= 1) { unsigned long long o = shflxor64(best, m); if (o > best) best = o; }
        if (lane == 0) part[s & 1][t >> 6] = best;
        __syncthreads();
        unsigned long long v = part[s & 1][lane & 15];
#pragma unroll
        for (int m = 8; m; m >>= 1) { unsigned long long o = shflxor64(v, m); if (o > v) v = o; }
        cur = 4095 - (int)(unsigned)(v & 0xffffffffu);
        cx = lx[cur]; cy = ly[cur]; cz = lz[cur];
    }
}

// ---------------- kNN (top-32 smallest d2, expansion form) + new_xyz write ------
__global__ __launch_bounds__(256) void knn_kernel(const float* __restrict__ xyz,
                                                  const int* __restrict__ fps_idx,
                                                  int* __restrict__ knn,
                                                  float* __restrict__ out) {
    __shared__ float lx[NN], ly[NN], lz[NN], pn[NN];
    __shared__ unsigned long long part[2][4];
    const int b = blockIdx.x >> 6, rb = blockIdx.x & 63, t = threadIdx.x;
    for (int p = t; p < NN; p += 256) {
        const float* xr = xyz + ((size_t)(b << 12) + p) * 3;
        float x = xr[0], y = xr[1], z = xr[2];
        lx[p] = x; ly[p] = y; lz[p] = z;
        pn[p] = __fadd_rn(__fadd_rn(__fmul_rn(x, x), __fmul_rn(y, y)), __fmul_rn(z, z));
    }
    __syncthreads();
    const int lane = t & 63, wv = t >> 6;
    for (int r = 0; r < 16; ++r) {
        const int s = (rb << 4) + r;
        const int ci = fps_idx[(b << 10) + s];
        const float cx = lx[ci], cy = ly[ci], cz = lz[ci];
        const float cn = __fadd_rn(__fadd_rn(__fmul_rn(cx, cx), __fmul_rn(cy, cy)), __fmul_rn(cz, cz));
        if (t < 3) out[((size_t)(b << 10) + s) * 3 + t] = (t == 0) ? cx : (t == 1 ? cy : cz);
        unsigned long long key[16];
#pragma unroll
        for (int i = 0; i < 16; ++i) {
            int p = t + (i << 8);
            float dot = __fadd_rn(__fadd_rn(__fmul_rn(cx, lx[p]), __fmul_rn(cy, ly[p])),
                                  __fmul_rn(cz, lz[p]));
            float d2 = __fsub_rn(__fadd_rn(cn, pn[p]), __fmul_rn(2.0f, dot));
            unsigned u = __float_as_uint(d2);
            unsigned enc = u ^ ((unsigned)((int)u >> 31) | 0x80000000u);
            key[i] = ((unsigned long long)enc << 32) | (unsigned)p;
        }
        unsigned long long lm = key[0];
#pragma unroll
        for (int i = 1; i < 16; ++i) lm = key[i] < lm ? key[i] : lm;
        const int rowbase = ((b << 10) + s) << 5;
        for (int j = 0; j < 32; ++j) {
            unsigned long long v = lm;
#pragma unroll
            for (int m = 32; m; m >>= 1) { unsigned long long o = shflxor64(v, m); if (o < v) v = o; }
            if (lane == 0) part[j & 1][wv] = v;
            __syncthreads();
            unsigned long long w = part[j & 1][lane & 3];
            { unsigned long long o = shflxor64(w, 2); if (o < w) w = o;
              o = shflxor64(w, 1); if (o < w) w = o; }
            const unsigned wp = (unsigned)(w & 0xffffffffu);
            if (t == 0) knn[rowbase + j] = (int)wp;
            if ((int)(wp & 255u) == t) {
#pragma unroll
                for (int i = 0; i < 16; ++i) if (key[i] == w) key[i] = ~0ULL;
                lm = key[0];
#pragma unroll
                for (int i = 1; i < 16; ++i) lm = key[i] < lm ? key[i] : lm;
            }
        }
    }
}

// ---------------- conv0: gather h, y0 = w0 h + b0, store Y0 (ch-major), stats ---
template <typename YT>
__global__ __launch_bounds__(256) void conv0_kernel(
    const float* __restrict__ xyz, const float* __restrict__ points,
    const float* __restrict__ out_xyz, const int* __restrict__ knn,
    const float* __restrict__ w0, const float* __restrict__ b0,
    YT* __restrict__ Y0, float* __restrict__ gs, float* __restrict__ gq) {
    __shared__ float wsh[64 * 68];
    __shared__ float bsm[64], bqm[64];
    const int t = threadIdx.x;
    for (int i = t; i < 64 * 68; i += 256) {
        int row = i / 68, col = i - row * 68;
        wsh[i] = (col < CIN) ? w0[row * CIN + col] : 0.f;
    }
    if (t < 64) { bsm[t] = 0.f; bqm[t] = 0.f; }
    __syncthreads();
    const int e = blockIdx.x * 256 + t;
    const int b = e >> 15, s = (e >> 5) & 1023;
    const int pidx = knn[e];
    float h[68];
    {
        const float* xr = xyz + ((size_t)(b << 12) + pidx) * 3;
        const float* cr = out_xyz + ((size_t)(b << 10) + s) * 3;
        h[0] = xr[0] - cr[0]; h[1] = xr[1] - cr[1]; h[2] = xr[2] - cr[2];
        const float4* pr = (const float4*)(points + (((size_t)(b << 12) + pidx) << 6));
#pragma unroll
        for (int j = 0; j < 16; ++j) {
            float4 v = pr[j];
            h[3 + 4 * j] = v.x; h[4 + 4 * j] = v.y; h[5 + 4 * j] = v.z; h[6 + 4 * j] = v.w;
        }
        h[67] = 0.f;
    }
    for (int o = 0; o < 64; ++o) {
        float acc = b0[o];
#pragma unroll
        for (int c = 0; c < 68; ++c) acc += wsh[o * 68 + c] * h[c];
        stY(&Y0[(size_t)o * MTOT + e], acc);
        float s1 = acc, s2 = acc * acc;
#pragma unroll
        for (int m = 32; m; m >>= 1) { s1 += __shfl_xor(s1, m); s2 += __shfl_xor(s2, m); }
        if ((t & 63) == 0) { atomicAdd(&bsm[o], s1); atomicAdd(&bqm[o], s2); }
    }
    __syncthreads();
    if (t < 64) atomicAdd(&gs[t], bsm[t]);
    else if (t < 128) atomicAdd(&gq[t - 64], bqm[t - 64]);
}

// ---------------- conv1: a0 = relu(bn0(Y0)), y1 = w1 a0 + b1, store Y1, stats ---
template <typename YT>
__global__ __launch_bounds__(256) void conv1_kernel(
    const YT* __restrict__ Y0, const float* __restrict__ w1, const float* __restrict__ b1,
    const float* __restrict__ sc, const float* __restrict__ sh,
    YT* __restrict__ Y1, float* __restrict__ gs, float* __restrict__ gq) {
    __shared__ float wsh[64 * 64];
    __shared__ float bsm[64], bqm[64];
    const int t = threadIdx.x;
    for (int i = t; i < 64 * 64; i += 256) wsh[i] = w1[i];
    if (t < 64) { bsm[t] = 0.f; bqm[t] = 0.f; }
    __syncthreads();
    const int e = blockIdx.x * 256 + t;
    float a[64];
#pragma unroll
    for (int c = 0; c < 64; ++c) {
        float y = ldY(&Y0[(size_t)c * MTOT + e]);
        a[c] = fmaxf(sc[c] * y + sh[c], 0.f);
    }
    for (int o = 0; o < 64; ++o) {
        float acc = b1[o];
#pragma unroll
        for (int c = 0; c < 64; ++c) acc += wsh[o * 64 + c] * a[c];
        stY(&Y1[(size_t)o * MTOT + e], acc);
        float s1 = acc, s2 = acc * acc;
#pragma unroll
        for (int m = 32; m; m >>= 1) { s1 += __shfl_xor(s1, m); s2 += __shfl_xor(s2, m); }
        if ((t & 63) == 0) { atomicAdd(&bsm[o], s1); atomicAdd(&bqm[o], s2); }
    }
    __syncthreads();
    if (t < 64) atomicAdd(&gs[t], bsm[t]);
    else if (t < 128) atomicAdd(&gq[t - 64], bqm[t - 64]);
}

// ---------------- conv2 stats only: a1 = relu(bn1(Y1)), y2 = w2 a1 + b2 ---------
template <typename YT>
__global__ __launch_bounds__(256) void conv2s_kernel(
    const YT* __restrict__ Y1, const float* __restrict__ w2, const float* __restrict__ b2,
    const float* __restrict__ sc, const float* __restrict__ sh,
    float* __restrict__ gs, float* __restrict__ gq) {
    __shared__ float wsh[128 * 64];
    __shared__ float bsm[128], bqm[128];
    const int t = threadIdx.x;
    for (int i = t; i < 128 * 64; i += 256) wsh[i] = w2[i];
    if (t < 128) { bsm[t] = 0.f; bqm[t] = 0.f; }
    __syncthreads();
    const int e = blockIdx.x * 256 + t;
    float a[64];
#pragma unroll
    for (int c = 0; c < 64; ++c) {
        float y = ldY(&Y1[(size_t)c * MTOT + e]);
        a[c] = fmaxf(sc[c] * y + sh[c], 0.f);
    }
    for (int o = 0; o < 128; ++o) {
        float acc = b2[o];
#pragma unroll
        for (int c = 0; c < 64; ++c) acc += wsh[o * 64 + c] * a[c];
        float s1 = acc, s2 = acc * acc;
#pragma unroll
        for (int m = 32; m; m >>= 1) { s1 += __shfl_xor(s1, m); s2 += __shfl_xor(s2, m); }
        if ((t & 63) == 0) { atomicAdd(&bsm[o], s1); atomicAdd(&bqm[o], s2); }
    }
    __syncthreads();
    if (t < 128) atomicAdd(&gs[t], bsm[t]);
    else atomicAdd(&gq[t - 128], bqm[t - 128]);
}

// ---------------- final: y2 -> bn2 -> relu -> max over k -> transposed write ----
template <typename YT>
__global__ __launch_bounds__(256) void final_kernel(
    const YT* __restrict__ Y1, const float* __restrict__ w2, const float* __restrict__ b2,
    const float* __restrict__ sc1, const float* __restrict__ sh1,
    const float* __restrict__ sc2, const float* __restrict__ sh2,
    float* __restrict__ out) {
    __shared__ float wsh[128 * 64];
    __shared__ float trans[128 * 8];
    const int t = threadIdx.x;
    for (int i = t; i < 128 * 64; i += 256) wsh[i] = w2[i];
    __syncthreads();
    const int e = blockIdx.x * 256 + t;
    float a[64];
#pragma unroll
    for (int c = 0; c < 64; ++c) {
        float y = ldY(&Y1[(size_t)c * MTOT + e]);
        a[c] = fmaxf(sc1[c] * y + sh1[c], 0.f);
    }
    const int R0 = blockIdx.x * 8;
    const int b = R0 >> 10, s_base = R0 & 1023;
    const int row = t >> 5;
    for (int o = 0; o < 128; ++o) {
        float acc = b2[o];
#pragma unroll
        for (int c = 0; c < 64; ++c) acc += wsh[o * 64 + c] * a[c];
        float v = fmaxf(sc2[o] * acc + sh2[o], 0.f);
#pragma unroll
        for (int m = 16; m; m >>= 1) v = fmaxf(v, __shfl_xor(v, m));
        if ((t & 31) == 0) trans[o * 8 + row] = v;
    }
    __syncthreads();
    float* np = out + NEWP_OFF;
    for (int i = t; i < 1024; i += 256) {
        int o = i >> 3, r = i & 7;
        np[((size_t)b * 128 + o) * 1024 + s_base + r] = trans[i];
    }
}

// ---------------- finalize BN: scale/shift from sums ---------------------------
__global__ void fin_kernel(const float* __restrict__ gs, const float* __restrict__ gq,
                           const float* __restrict__ g, const float* __restrict__ bb,
                           float* __restrict__ sc, float* __restrict__ sh, int C) {
    const int o = threadIdx.x;
    if (o < C) {
        const float inv = 1.f / (float)MTOT;
        float mean = gs[o] * inv;
        float var = gq[o] * inv - mean * mean;
        float r = g[o] / sqrtf(var + 1e-5f);
        sc[o] = r;
        sh[o] = bb[o] - mean * r;
    }
}

extern "C" void kernel_launch(void* const* d_in, const int* in_sizes, int n_in,
                              void* d_out, int out_size, void* d_ws, size_t ws_size,
                              hipStream_t stream) {
    const float* xyz = (const float*)d_in[0];
    const float* points = (const float*)d_in[1];
    const float* w0 = (const float*)d_in[2];
    const float* b0 = (const float*)d_in[3];
    const float* g0 = (const float*)d_in[4];
    const float* bb0 = (const float*)d_in[5];
    const float* w1 = (const float*)d_in[6];
    const float* b1 = (const float*)d_in[7];
    const float* g1 = (const float*)d_in[8];
    const float* bb1 = (const float*)d_in[9];
    const float* w2 = (const float*)d_in[10];
    const float* b2 = (const float*)d_in[11];
    const float* g2 = (const float*)d_in[12];
    const float* bb2 = (const float*)d_in[13];
    float* out = (float*)d_out;
    char* ws = (char*)d_ws;

    int* knn = (int*)(ws);                              // 2 MiB
    int* fps = (int*)(ws + (2u << 20));                 // 64 KiB
    float* stats = (float*)(ws + (2u << 20) + (1u << 16));
    float* bn = stats + 512;
    float *gs0 = stats, *gq0 = stats + 64, *gs1 = stats + 128, *gq1 = stats + 192;
    float *gs2 = stats + 256, *gq2 = stats + 384;
    float *sc0 = bn, *sh0 = bn + 64, *sc1 = bn + 128, *sh1 = bn + 192;
    float *sc2 = bn + 256, *sh2 = bn + 384;
    const size_t yoff = 4u << 20;
    const size_t ybytes_f32 = (size_t)MTOT * 64 * 4;
    const bool f32p = ws_size >= yoff + 2 * ybytes_f32;

    hipMemsetAsync(stats, 0, 512 * sizeof(float), stream);
    fps_kernel<<<NB, 1024, 0, stream>>>(xyz, fps);
    knn_kernel<<<NB * 64, 256, 0, stream>>>(xyz, fps, knn, out);

    if (f32p) {
        float* Y0 = (float*)(ws + yoff);
        float* Y1 = Y0 + (size_t)MTOT * 64;
        conv0_kernel<float><<<2048, 256, 0, stream>>>(xyz, points, out, knn, w0, b0, Y0, gs0, gq0);
        fin_kernel<<<1, 64, 0, stream>>>(gs0, gq0, g0, bb0, sc0, sh0, 64);
        conv1_kernel<float><<<2048, 256, 0, stream>>>(Y0, w1, b1, sc0, sh0, Y1, gs1, gq1);
        fin_kernel<<<1, 64, 0, stream>>>(gs1, gq1, g1, bb1, sc1, sh1, 64);
        conv2s_kernel<float><<<2048, 256, 0, stream>>>(Y1, w2, b2, sc1, sh1, gs2, gq2);
        fin_kernel<<<1, 128, 0, stream>>>(gs2, gq2, g2, bb2, sc2, sh2, 128);
        final_kernel<float><<<2048, 256, 0, stream>>>(Y1, w2, b2, sc1, sh1, sc2, sh2, out);
    } else {
        __hip_bfloat16* Y0 = (__hip_bfloat16*)(ws + yoff);
        __hip_bfloat16* Y1 = Y0 + (size_t)MTOT * 64;
        conv0_kernel<__hip_bfloat16><<<2048, 256, 0, stream>>>(xyz, points, out, knn, w0, b0, Y0, gs0, gq0);
        fin_kernel<<<1, 64, 0, stream>>>(gs0, gq0, g0, bb0, sc0, sh0, 64);
        conv1_kernel<__hip_bfloat16><<<2048, 256, 0, stream>>>(Y0, w1, b1, sc0, sh0, Y1, gs1, gq1);
        fin_kernel<<<1, 64, 0, stream>>>(gs1, gq1, g1, bb1, sc1, sh1, 64);
        conv2s_kernel<__hip_bfloat16><<<2048, 256, 0, stream>>>(Y1, w2, b2, sc1, sh1, gs2, gq2);
        fin_kernel<<<1, 128, 0, stream>>>(gs2, gq2, g2, bb2, sc2, sh2, 128);
        final_kernel<__hip_bfloat16><<<2048, 256, 0, stream>>>(Y1, w2, b2, sc1, sh1, sc2, sh2, out);
    }
}

// Round 2
// 1880.898 us; speedup vs baseline: 1.5274x; 1.5274x over previous
//
#include <hip/hip_runtime.h>
#include <hip/hip_bf16.h>

#define NB 16
#define NN 4096
#define NS 1024
#define NK 32
#define CF 64
#define CIN 67
#define MTOT 524288          // NB*NS*NK
#define NEWP_OFF 49152       // NB*NS*3

__device__ inline unsigned long long shflxor64(unsigned long long v, int m) {
    int lo = __shfl_xor((int)(unsigned)(v & 0xffffffffULL), m);
    int hi = __shfl_xor((int)(unsigned)(v >> 32), m);
    return ((unsigned long long)(unsigned)hi << 32) | (unsigned)lo;
}

__device__ inline void stY(float* p, float v) { *p = v; }
__device__ inline void stY(__hip_bfloat16* p, float v) { *p = __float2bfloat16(v); }
__device__ inline float ldY(const float* p) { return *p; }
__device__ inline float ldY(const __hip_bfloat16* p) { return __bfloat162float(*p); }

// ---------------- FPS: 16 blocks (one per batch), 256 threads, 16 pts/thread ----
__global__ __launch_bounds__(256) void fps_kernel(const float* __restrict__ xyz,
                                                  int* __restrict__ fps_idx) {
    __shared__ float lx[NN], ly[NN], lz[NN];
    __shared__ unsigned long long part[2][4];
    const int b = blockIdx.x, t = threadIdx.x;
    const float4* src = (const float4*)(xyz + (size_t)b * NN * 3);
    float px[16], py[16], pz[16], dist[16];
#pragma unroll
    for (int j = 0; j < 4; ++j) {
        float4 A = src[t * 12 + 3 * j], B4 = src[t * 12 + 3 * j + 1], C4 = src[t * 12 + 3 * j + 2];
        px[4 * j + 0] = A.x;  py[4 * j + 0] = A.y;  pz[4 * j + 0] = A.z;
        px[4 * j + 1] = A.w;  py[4 * j + 1] = B4.x; pz[4 * j + 1] = B4.y;
        px[4 * j + 2] = B4.z; py[4 * j + 2] = B4.w; pz[4 * j + 2] = C4.x;
        px[4 * j + 3] = C4.y; py[4 * j + 3] = C4.z; pz[4 * j + 3] = C4.w;
    }
#pragma unroll
    for (int i = 0; i < 16; ++i) {
        dist[i] = 1e10f;
        lx[16 * t + i] = px[i]; ly[16 * t + i] = py[i]; lz[16 * t + i] = pz[i];
    }
    __syncthreads();
    int cur = 0;
    float cx = lx[0], cy = ly[0], cz = lz[0];
    const int lane = t & 63, wv = t >> 6;
    const unsigned invbase = 4095u - 16u * (unsigned)t;
    for (int s = 0; s < NS; ++s) {
        if (t == 0) fps_idx[(b << 10) + s] = cur;
        unsigned long long best = 0;
#pragma unroll
        for (int i = 0; i < 16; ++i) {
            float dx = __fsub_rn(px[i], cx), dy = __fsub_rn(py[i], cy), dz = __fsub_rn(pz[i], cz);
            float d = __fadd_rn(__fadd_rn(__fmul_rn(dx, dx), __fmul_rn(dy, dy)), __fmul_rn(dz, dz));
            dist[i] = fminf(dist[i], d);
            unsigned long long key =
                ((unsigned long long)__float_as_uint(dist[i]) << 32) | (invbase - i);
            best = key > best ? key : best;
        }
#pragma unroll
        for (int m = 32; m; m >>= 1) { unsigned long long o = shflxor64(best, m); if (o > best) best = o; }
        if (lane == 0) part[s & 1][wv] = best;
        __syncthreads();
        unsigned long long v = part[s & 1][lane & 3];
        { unsigned long long o = shflxor64(v, 2); if (o > v) v = o;
          o = shflxor64(v, 1); if (o > v) v = o; }
        cur = 4095 - (int)(unsigned)(v & 0xffffffffu);
        cx = lx[cur]; cy = ly[cur]; cz = lz[cur];
    }
}

// ---------------- kNN: wave-private top-32 extraction (no barriers in loop) -----
__global__ __launch_bounds__(256) void knn_kernel(const float* __restrict__ xyz,
                                                  const int* __restrict__ fps_idx,
                                                  int* __restrict__ knn,
                                                  float* __restrict__ out) {
    __shared__ float lx[NN], ly[NN], lz[NN], pn[NN];
    const int b = blockIdx.x >> 5, cb = blockIdx.x & 31, t = threadIdx.x;
    for (int p = t; p < NN; p += 256) {
        const float* xr = xyz + ((size_t)(b << 12) + p) * 3;
        float x = xr[0], y = xr[1], z = xr[2];
        lx[p] = x; ly[p] = y; lz[p] = z;
        pn[p] = __fadd_rn(__fadd_rn(__fmul_rn(x, x), __fmul_rn(y, y)), __fmul_rn(z, z));
    }
    __syncthreads();
    const int lane = t & 63, wv = t >> 6;
    for (int r = 0; r < 8; ++r) {
        const int s = (cb << 5) + (wv << 3) + r;
        const int ci = fps_idx[(b << 10) + s];
        const float cx = lx[ci], cy = ly[ci], cz = lz[ci];
        const float cn = __fadd_rn(__fadd_rn(__fmul_rn(cx, cx), __fmul_rn(cy, cy)), __fmul_rn(cz, cz));
        if (lane < 3) out[((size_t)(b << 10) + s) * 3 + lane] = (lane == 0) ? cx : (lane == 1 ? cy : cz);
        // build per-lane sorted top-3 of 64 candidates
        unsigned long long m1 = ~0ULL, m2 = ~0ULL, m3 = ~0ULL;
#pragma unroll
        for (int i = 0; i < 64; ++i) {
            int p = lane + (i << 6);
            float dot = __fadd_rn(__fadd_rn(__fmul_rn(cx, lx[p]), __fmul_rn(cy, ly[p])),
                                  __fmul_rn(cz, lz[p]));
            float d2 = __fsub_rn(__fadd_rn(cn, pn[p]), __fmul_rn(2.0f, dot));
            unsigned u = __float_as_uint(d2);
            unsigned enc = u ^ ((unsigned)((int)u >> 31) | 0x80000000u);
            unsigned long long key = ((unsigned long long)enc << 32) | (unsigned)p;
            if (key < m3) {
                if (key < m1)      { m3 = m2; m2 = m1; m1 = key; }
                else if (key < m2) { m3 = m2; m2 = key; }
                else               { m3 = key; }
            }
        }
        unsigned myidx = 0;
        for (int j = 0; j < 32; ++j) {
            unsigned long long v = m1;
#pragma unroll
            for (int m = 32; m; m >>= 1) { unsigned long long o = shflxor64(v, m); if (o < v) v = o; }
            if (lane == j) myidx = (unsigned)(v & 0xffffffffu);
            if (v == m1) {   // unique owner (keys unique)
                m1 = m2; m2 = m3; m3 = ~0ULL;
                if (m1 == ~0ULL) {
                    // refill: all remaining keys of this lane are > v (global order)
#pragma unroll
                    for (int i = 0; i < 64; ++i) {
                        int p = lane + (i << 6);
                        float dot = __fadd_rn(__fadd_rn(__fmul_rn(cx, lx[p]), __fmul_rn(cy, ly[p])),
                                              __fmul_rn(cz, lz[p]));
                        float d2 = __fsub_rn(__fadd_rn(cn, pn[p]), __fmul_rn(2.0f, dot));
                        unsigned u = __float_as_uint(d2);
                        unsigned enc = u ^ ((unsigned)((int)u >> 31) | 0x80000000u);
                        unsigned long long key = ((unsigned long long)enc << 32) | (unsigned)p;
                        if (key > v && key < m3) {
                            if (key < m1)      { m3 = m2; m2 = m1; m1 = key; }
                            else if (key < m2) { m3 = m2; m2 = key; }
                            else               { m3 = key; }
                        }
                    }
                }
            }
        }
        const int rowbase = ((b << 10) + s) << 5;
        if (lane < 32) knn[rowbase + lane] = (int)myidx;
    }
}

// ---------------- conv0: gather h, y0 = w0 h + b0, store Y0 (ch-major), stats ---
template <typename YT>
__global__ __launch_bounds__(256) void conv0_kernel(
    const float* __restrict__ xyz, const float* __restrict__ points,
    const float* __restrict__ out_xyz, const int* __restrict__ knn,
    const float* __restrict__ w0, const float* __restrict__ b0,
    YT* __restrict__ Y0, float* __restrict__ gs, float* __restrict__ gq) {
    __shared__ float wsh[64 * 68];
    __shared__ float bsm[64], bqm[64];
    const int t = threadIdx.x;
    for (int i = t; i < 64 * 68; i += 256) {
        int row = i / 68, col = i - row * 68;
        wsh[i] = (col < CIN) ? w0[row * CIN + col] : 0.f;
    }
    if (t < 64) { bsm[t] = 0.f; bqm[t] = 0.f; }
    __syncthreads();
    const int e = blockIdx.x * 256 + t;
    const int b = e >> 15, s = (e >> 5) & 1023;
    const int pidx = knn[e];
    float h[68];
    {
        const float* xr = xyz + ((size_t)(b << 12) + pidx) * 3;
        const float* cr = out_xyz + ((size_t)(b << 10) + s) * 3;
        h[0] = xr[0] - cr[0]; h[1] = xr[1] - cr[1]; h[2] = xr[2] - cr[2];
        const float4* pr = (const float4*)(points + (((size_t)(b << 12) + pidx) << 6));
#pragma unroll
        for (int j = 0; j < 16; ++j) {
            float4 v = pr[j];
            h[3 + 4 * j] = v.x; h[4 + 4 * j] = v.y; h[5 + 4 * j] = v.z; h[6 + 4 * j] = v.w;
        }
        h[67] = 0.f;
    }
    for (int o = 0; o < 64; ++o) {
        float acc = b0[o];
#pragma unroll
        for (int c = 0; c < 68; ++c) acc += wsh[o * 68 + c] * h[c];
        stY(&Y0[(size_t)o * MTOT + e], acc);
        float s1 = acc, s2 = acc * acc;
#pragma unroll
        for (int m = 32; m; m >>= 1) { s1 += __shfl_xor(s1, m); s2 += __shfl_xor(s2, m); }
        if ((t & 63) == 0) { atomicAdd(&bsm[o], s1); atomicAdd(&bqm[o], s2); }
    }
    __syncthreads();
    if (t < 64) atomicAdd(&gs[t], bsm[t]);
    else if (t < 128) atomicAdd(&gq[t - 64], bqm[t - 64]);
}

// ---------------- conv1: a0 = relu(bn0(Y0)), y1 = w1 a0 + b1, store Y1, stats ---
template <typename YT>
__global__ __launch_bounds__(256) void conv1_kernel(
    const YT* __restrict__ Y0, const float* __restrict__ w1, const float* __restrict__ b1,
    const float* __restrict__ sc, const float* __restrict__ sh,
    YT* __restrict__ Y1, float* __restrict__ gs, float* __restrict__ gq) {
    __shared__ float wsh[64 * 64];
    __shared__ float bsm[64], bqm[64];
    const int t = threadIdx.x;
    for (int i = t; i < 64 * 64; i += 256) wsh[i] = w1[i];
    if (t < 64) { bsm[t] = 0.f; bqm[t] = 0.f; }
    __syncthreads();
    const int e = blockIdx.x * 256 + t;
    float a[64];
#pragma unroll
    for (int c = 0; c < 64; ++c) {
        float y = ldY(&Y0[(size_t)c * MTOT + e]);
        a[c] = fmaxf(sc[c] * y + sh[c], 0.f);
    }
    for (int o = 0; o < 64; ++o) {
        float acc = b1[o];
#pragma unroll
        for (int c = 0; c < 64; ++c) acc += wsh[o * 64 + c] * a[c];
        stY(&Y1[(size_t)o * MTOT + e], acc);
        float s1 = acc, s2 = acc * acc;
#pragma unroll
        for (int m = 32; m; m >>= 1) { s1 += __shfl_xor(s1, m); s2 += __shfl_xor(s2, m); }
        if ((t & 63) == 0) { atomicAdd(&bsm[o], s1); atomicAdd(&bqm[o], s2); }
    }
    __syncthreads();
    if (t < 64) atomicAdd(&gs[t], bsm[t]);
    else if (t < 128) atomicAdd(&gq[t - 64], bqm[t - 64]);
}

// ------- conv2s: a1 = relu(bn1(Y1)), y2 = w2 a1 + b2; stats + per-(s,o) max/min -
template <typename YT>
__global__ __launch_bounds__(256) void conv2s_kernel(
    const YT* __restrict__ Y1, const float* __restrict__ w2, const float* __restrict__ b2,
    const float* __restrict__ sc, const float* __restrict__ sh,
    float* __restrict__ gs, float* __restrict__ gq,
    float* __restrict__ Mx, float* __restrict__ Mn) {
    __shared__ float wsh[128 * 64];
    __shared__ float bsm[128], bqm[128];
    const int t = threadIdx.x;
    for (int i = t; i < 128 * 64; i += 256) wsh[i] = w2[i];
    if (t < 128) { bsm[t] = 0.f; bqm[t] = 0.f; }
    __syncthreads();
    const int e = blockIdx.x * 256 + t;
    const int sidx = e >> 5;
    float a[64];
#pragma unroll
    for (int c = 0; c < 64; ++c) {
        float y = ldY(&Y1[(size_t)c * MTOT + e]);
        a[c] = fmaxf(sc[c] * y + sh[c], 0.f);
    }
    for (int o = 0; o < 128; ++o) {
        float acc = b2[o];
#pragma unroll
        for (int c = 0; c < 64; ++c) acc += wsh[o * 64 + c] * a[c];
        float s1 = acc, s2 = acc * acc;
#pragma unroll
        for (int m = 32; m; m >>= 1) { s1 += __shfl_xor(s1, m); s2 += __shfl_xor(s2, m); }
        if ((t & 63) == 0) { atomicAdd(&bsm[o], s1); atomicAdd(&bqm[o], s2); }
        float mx = acc, mn = acc;
#pragma unroll
        for (int m = 16; m; m >>= 1) {
            mx = fmaxf(mx, __shfl_xor(mx, m));
            mn = fminf(mn, __shfl_xor(mn, m));
        }
        if ((t & 31) == 0) {
            Mx[(size_t)sidx * 128 + o] = mx;
            Mn[(size_t)sidx * 128 + o] = mn;
        }
    }
    __syncthreads();
    if (t < 128) atomicAdd(&gs[t], bsm[t]);
    else atomicAdd(&gq[t - 128], bqm[t - 128]);
}

// ---------------- final2: bn2 + relu applied to extreme over k, transposed write -
__global__ __launch_bounds__(256) void final2_kernel(
    const float* __restrict__ Mx, const float* __restrict__ Mn,
    const float* __restrict__ sc2, const float* __restrict__ sh2,
    float* __restrict__ out) {
    const int i = blockIdx.x * 256 + threadIdx.x;   // i = ((b*128+o)<<10)|s
    const int b = i >> 17, o = (i >> 10) & 127, s = i & 1023;
    const float a = sc2[o];
    const size_t src = ((size_t)(b << 10) + s) * 128 + o;
    const float m = (a >= 0.f) ? Mx[src] : Mn[src];
    out[NEWP_OFF + (size_t)i] = fmaxf(a * m + sh2[o], 0.f);
}

// ---------------- finalize BN: scale/shift from sums ---------------------------
__global__ void fin_kernel(const float* __restrict__ gs, const float* __restrict__ gq,
                           const float* __restrict__ g, const float* __restrict__ bb,
                           float* __restrict__ sc, float* __restrict__ sh, int C) {
    const int o = threadIdx.x;
    if (o < C) {
        const float inv = 1.f / (float)MTOT;
        float mean = gs[o] * inv;
        float var = gq[o] * inv - mean * mean;
        float r = g[o] / sqrtf(var + 1e-5f);
        sc[o] = r;
        sh[o] = bb[o] - mean * r;
    }
}

extern "C" void kernel_launch(void* const* d_in, const int* in_sizes, int n_in,
                              void* d_out, int out_size, void* d_ws, size_t ws_size,
                              hipStream_t stream) {
    const float* xyz = (const float*)d_in[0];
    const float* points = (const float*)d_in[1];
    const float* w0 = (const float*)d_in[2];
    const float* b0 = (const float*)d_in[3];
    const float* g0 = (const float*)d_in[4];
    const float* bb0 = (const float*)d_in[5];
    const float* w1 = (const float*)d_in[6];
    const float* b1 = (const float*)d_in[7];
    const float* g1 = (const float*)d_in[8];
    const float* bb1 = (const float*)d_in[9];
    const float* w2 = (const float*)d_in[10];
    const float* b2 = (const float*)d_in[11];
    const float* g2 = (const float*)d_in[12];
    const float* bb2 = (const float*)d_in[13];
    float* out = (float*)d_out;
    char* ws = (char*)d_ws;

    int* knn = (int*)(ws);                               // 2 MiB
    int* fps = (int*)(ws + (2u << 20));                  // 64 KiB
    float* stats = (float*)(ws + (2u << 20) + (1u << 16));
    float* bn = stats + 512;
    float *gs0 = stats, *gq0 = stats + 64, *gs1 = stats + 128, *gq1 = stats + 192;
    float *gs2 = stats + 256, *gq2 = stats + 384;
    float *sc0 = bn, *sh0 = bn + 64, *sc1 = bn + 128, *sh1 = bn + 192;
    float *sc2 = bn + 256, *sh2 = bn + 384;
    float* Mx = (float*)(ws + (4ull << 20));             // 8 MiB
    float* Mn = (float*)(ws + (12ull << 20));            // 8 MiB
    const size_t yoff = 20ull << 20;
    const size_t ybytes_f32 = (size_t)MTOT * 64 * 4;
    const bool f32p = ws_size >= yoff + 2 * ybytes_f32;

    hipMemsetAsync(stats, 0, 512 * sizeof(float), stream);
    fps_kernel<<<NB, 256, 0, stream>>>(xyz, fps);
    knn_kernel<<<NB * 32, 256, 0, stream>>>(xyz, fps, knn, out);

    if (f32p) {
        float* Y0 = (float*)(ws + yoff);
        float* Y1 = Y0 + (size_t)MTOT * 64;
        conv0_kernel<float><<<2048, 256, 0, stream>>>(xyz, points, out, knn, w0, b0, Y0, gs0, gq0);
        fin_kernel<<<1, 64, 0, stream>>>(gs0, gq0, g0, bb0, sc0, sh0, 64);
        conv1_kernel<float><<<2048, 256, 0, stream>>>(Y0, w1, b1, sc0, sh0, Y1, gs1, gq1);
        fin_kernel<<<1, 64, 0, stream>>>(gs1, gq1, g1, bb1, sc1, sh1, 64);
        conv2s_kernel<float><<<2048, 256, 0, stream>>>(Y1, w2, b2, sc1, sh1, gs2, gq2, Mx, Mn);
        fin_kernel<<<1, 128, 0, stream>>>(gs2, gq2, g2, bb2, sc2, sh2, 128);
    } else {
        __hip_bfloat16* Y0 = (__hip_bfloat16*)(ws + yoff);
        __hip_bfloat16* Y1 = Y0 + (size_t)MTOT * 64;
        conv0_kernel<__hip_bfloat16><<<2048, 256, 0, stream>>>(xyz, points, out, knn, w0, b0, Y0, gs0, gq0);
        fin_kernel<<<1, 64, 0, stream>>>(gs0, gq0, g0, bb0, sc0, sh0, 64);
        conv1_kernel<__hip_bfloat16><<<2048, 256, 0, stream>>>(Y0, w1, b1, sc0, sh0, Y1, gs1, gq1);
        fin_kernel<<<1, 64, 0, stream>>>(gs1, gq1, g1, bb1, sc1, sh1, 64);
        conv2s_kernel<__hip_bfloat16><<<2048, 256, 0, stream>>>(Y1, w2, b2, sc1, sh1, gs2, gq2, Mx, Mn);
        fin_kernel<<<1, 128, 0, stream>>>(gs2, gq2, g2, bb2, sc2, sh2, 128);
    }
    final2_kernel<<<8192, 256, 0, stream>>>(Mx, Mn, sc2, sh2, out);
}